// Round 3
// baseline (327.715 us; speedup 1.0000x reference)
//
#include <hip/hip_runtime.h>

#define N_NODES 50000
#define N_EDGES 800000
#define N_GRAPHS 512
#define FDIM 128

constexpr int SCAN_TILE = 256;
constexpr int NB = (N_NODES + SCAN_TILE - 1) / SCAN_TILE;  // 196

typedef __bf16 bf16x8 __attribute__((ext_vector_type(8)));
typedef float f32x4 __attribute__((ext_vector_type(4)));

__device__ __forceinline__ unsigned short f2bf(float f) {
  unsigned int u = __float_as_uint(f);
  unsigned int r = (u + 0x7FFFu + ((u >> 16) & 1u)) >> 16;
  return (unsigned short)r;
}
__device__ __forceinline__ float bflo(unsigned int v) {
  return __uint_as_float(v << 16);
}
__device__ __forceinline__ float bfhi(unsigned int v) {
  return __uint_as_float(v & 0xFFFF0000u);
}

__global__ void k_init(int* __restrict__ cnt, int* __restrict__ fill,
                       float* __restrict__ out) {
  int i = blockIdx.x * blockDim.x + threadIdx.x;
  if (i < N_NODES) { cnt[i] = 0; fill[i] = 0; }
  if (i < N_GRAPHS * FDIM) out[i] = 0.0f;
}

__global__ void k_count(const int* __restrict__ dst, int* __restrict__ cnt) {
  int e = blockIdx.x * blockDim.x + threadIdx.x;
  if (e < N_EDGES) atomicAdd(&cnt[dst[e]], 1);
}

__global__ void k_scan1(const int* __restrict__ cnt, int* __restrict__ row_ptr,
                        int* __restrict__ blk) {
  __shared__ int s[SCAN_TILE];
  int t = threadIdx.x;
  int i = blockIdx.x * SCAN_TILE + t;
  int v = (i < N_NODES) ? cnt[i] : 0;
  s[t] = v;
  __syncthreads();
  for (int d = 1; d < SCAN_TILE; d <<= 1) {
    int u = (t >= d) ? s[t - d] : 0;
    __syncthreads();
    s[t] += u;
    __syncthreads();
  }
  if (i < N_NODES) row_ptr[i] = s[t] - v;
  if (t == SCAN_TILE - 1) blk[blockIdx.x] = s[t];
}

__global__ void k_scan2(int* __restrict__ blk) {
  __shared__ int s[256];
  int t = threadIdx.x;
  int v = (t < NB) ? blk[t] : 0;
  s[t] = v;
  __syncthreads();
  for (int d = 1; d < 256; d <<= 1) {
    int u = (t >= d) ? s[t - d] : 0;
    __syncthreads();
    s[t] += u;
    __syncthreads();
  }
  if (t < NB) blk[t] = s[t] - v;
}

__global__ void k_scan3(const int* __restrict__ cnt, int* __restrict__ row_ptr,
                        const int* __restrict__ blk, float* __restrict__ dis) {
  int i = blockIdx.x * blockDim.x + threadIdx.x;
  if (i < N_NODES) {
    row_ptr[i] += blk[blockIdx.x];
    dis[i] = rsqrtf((float)(cnt[i] + 1));
  }
  if (i == 0) row_ptr[N_NODES] = N_EDGES;
}

// csr entry: (x_type[src], src, norm_bits, 0)
__global__ void k_fill(const int* __restrict__ src, const int* __restrict__ dst,
                       const int* __restrict__ x_type,
                       const int* __restrict__ row_ptr, int* __restrict__ fill,
                       const float* __restrict__ dis, int4* __restrict__ csr) {
  int e = blockIdx.x * blockDim.x + threadIdx.x;
  if (e >= N_EDGES) return;
  int s = src[e], d = dst[e];
  int pos = row_ptr[d] + atomicAdd(&fill[d], 1);
  csr[pos] = make_int4(x_type[s], s, __float_as_int(dis[s] * dis[d]), 0);
}

// W [128x128] f32 (k,n) -> Wt bf16 [n][k ^ ((n&15)<<3)]
__global__ void k_prep_w(const float* __restrict__ W0,
                         const float* __restrict__ W1,
                         unsigned short* __restrict__ Wt0,
                         unsigned short* __restrict__ Wt1) {
  int id = blockIdx.x * blockDim.x + threadIdx.x;  // 32768
  const float* W = (id >> 14) ? W1 : W0;
  unsigned short* Wt = (id >> 14) ? Wt1 : Wt0;
  int rem = id & 16383;
  int k = rem >> 7, n = rem & 127;
  Wt[n * 128 + (k ^ ((n & 15) << 3))] = f2bf(W[k * 128 + n]);
}

// Fused per-layer kernel: aggregate (f32 regs) -> bf16 LDS tile -> MFMA ->
// epilogue. Block = 64 rows, 4 waves; wave w owns rows [16w, 16w+16).
template <int LAYER>
__global__ __launch_bounds__(256) void k_layer(
    const int* __restrict__ x_type, const float* __restrict__ emb,
    const unsigned int* __restrict__ xin, const unsigned short* __restrict__ Wt,
    const float* __restrict__ bias, const int* __restrict__ row_ptr,
    const int4* __restrict__ csr, const float* __restrict__ dis,
    unsigned short* __restrict__ y, const int* __restrict__ batch,
    float* __restrict__ out) {
  __shared__ unsigned short Ws[128 * 128];  // 32 KB swizzled bf16 W^T
  __shared__ unsigned short xs[64 * 128];   // 16 KB swizzled bf16 A-tile
  int t = threadIdx.x;
  int w = t >> 6;
  int l = t & 63;
  int row0 = blockIdx.x * 64;

  // Async-stage W (8 KB per wave) — latency hides under phase A (T14).
  {
    const char* g = (const char*)Wt + w * 8192 + l * 16;
    char* ls = (char*)Ws + w * 8192;
#pragma unroll
    for (int i = 0; i < 8; ++i) {
      __builtin_amdgcn_global_load_lds(
          (const __attribute__((address_space(1))) unsigned int*)(g + i * 1024),
          (__attribute__((address_space(3))) unsigned int*)(ls + i * 1024), 16,
          0, 0);
    }
  }

  // Phase A: aggregate 16 nodes per wave, f32 accumulate, 2 feats/lane.
  for (int rr = 0; rr < 16; ++rr) {
    int node = row0 + w * 16 + rr;
    float ax = 0.f, ay = 0.f;
    if (node < N_NODES) {
      float di = dis[node];
      float w0 = di * di;
      if (LAYER == 1) {
        float2 v = ((const float2*)(emb + (size_t)x_type[node] * FDIM))[l];
        ax = v.x * w0;
        ay = v.y * w0;
      } else {
        unsigned int u = xin[(size_t)node * 64 + l];
        ax = bflo(u) * w0;
        ay = bfhi(u) * w0;
      }
      int j = row_ptr[node], end = row_ptr[node + 1];
      for (; j + 4 <= end; j += 4) {
        int4 e0 = csr[j], e1 = csr[j + 1], e2 = csr[j + 2], e3 = csr[j + 3];
        float n0 = __int_as_float(e0.z), n1 = __int_as_float(e1.z);
        float n2 = __int_as_float(e2.z), n3 = __int_as_float(e3.z);
        if (LAYER == 1) {
          float2 u0 = ((const float2*)(emb + (size_t)e0.x * FDIM))[l];
          float2 u1 = ((const float2*)(emb + (size_t)e1.x * FDIM))[l];
          float2 u2 = ((const float2*)(emb + (size_t)e2.x * FDIM))[l];
          float2 u3 = ((const float2*)(emb + (size_t)e3.x * FDIM))[l];
          ax = fmaf(u0.x, n0, ax); ay = fmaf(u0.y, n0, ay);
          ax = fmaf(u1.x, n1, ax); ay = fmaf(u1.y, n1, ay);
          ax = fmaf(u2.x, n2, ax); ay = fmaf(u2.y, n2, ay);
          ax = fmaf(u3.x, n3, ax); ay = fmaf(u3.y, n3, ay);
        } else {
          unsigned int u0 = xin[(size_t)e0.y * 64 + l];
          unsigned int u1 = xin[(size_t)e1.y * 64 + l];
          unsigned int u2 = xin[(size_t)e2.y * 64 + l];
          unsigned int u3 = xin[(size_t)e3.y * 64 + l];
          ax = fmaf(bflo(u0), n0, ax); ay = fmaf(bfhi(u0), n0, ay);
          ax = fmaf(bflo(u1), n1, ax); ay = fmaf(bfhi(u1), n1, ay);
          ax = fmaf(bflo(u2), n2, ax); ay = fmaf(bfhi(u2), n2, ay);
          ax = fmaf(bflo(u3), n3, ax); ay = fmaf(bfhi(u3), n3, ay);
        }
      }
      for (; j < end; ++j) {
        int4 e = csr[j];
        float nw = __int_as_float(e.z);
        if (LAYER == 1) {
          float2 u = ((const float2*)(emb + (size_t)e.x * FDIM))[l];
          ax = fmaf(u.x, nw, ax);
          ay = fmaf(u.y, nw, ay);
        } else {
          unsigned int u = xin[(size_t)e.y * 64 + l];
          ax = fmaf(bflo(u), nw, ax);
          ay = fmaf(bfhi(u), nw, ay);
        }
      }
    }
    // swizzled A-tile write: feats (2l, 2l+1) of local row w*16+rr.
    int chunk = (l >> 2) ^ rr;  // (row & 15) == rr
    ((unsigned int*)xs)[(w * 16 + rr) * 64 + chunk * 4 + (l & 3)] =
        (unsigned int)f2bf(ax) | ((unsigned int)f2bf(ay) << 16);
  }
  __syncthreads();  // Ws ready (drains vmcnt), xs ready

  // A fragments: lane l -> row (l&15), k = (l>>4)*8 + 32ks.
  bf16x8 a[4];
#pragma unroll
  for (int ks = 0; ks < 4; ++ks) {
    int chunk = ((l >> 4) + 4 * ks) ^ (l & 15);
    a[ks] = *(const bf16x8*)&xs[(w * 16 + (l & 15)) * 128 + chunk * 8];
  }

  f32x4 acc[8] = {};
#pragma unroll
  for (int ks = 0; ks < 4; ++ks) {
#pragma unroll
    for (int ct = 0; ct < 8; ++ct) {
      int n = ct * 16 + (l & 15);
      int kk = (ks * 32 + (l >> 4) * 8) ^ ((n & 15) << 3);
      bf16x8 b = *(const bf16x8*)&Ws[n * 128 + kk];
      acc[ct] =
          __builtin_amdgcn_mfma_f32_16x16x32_bf16(a[ks], b, acc[ct], 0, 0, 0);
    }
  }

  float bv[8];
#pragma unroll
  for (int ct = 0; ct < 8; ++ct) bv[ct] = bias[ct * 16 + (l & 15)];

  if (LAYER == 1) {
    // relu -> LDS (own rows; same-wave ordering) -> coalesced 1KB stores
#pragma unroll
    for (int r = 0; r < 4; ++r) {
      int lr = w * 16 + (l >> 4) * 4 + r;
#pragma unroll
      for (int ct = 0; ct < 8; ++ct) {
        float v = acc[ct][r] + bv[ct];
        xs[lr * 128 + ct * 16 + (l & 15)] = f2bf(fmaxf(v, 0.f));
      }
    }
#pragma unroll
    for (int i = 0; i < 4; ++i) {
      int row = row0 + w * 16 + i * 4 + (l >> 4);
      if (row < N_NODES) {
        float4 v = *(const float4*)((const char*)xs + w * 4096 + i * 1024 +
                                    l * 16);
        *(float4*)((char*)y + (size_t)(row0 + w * 16) * 256 + i * 1024 +
                   l * 16) = v;
      }
    }
  } else {
    // pooled output: run-length compress atomics (batch sorted)
    int g0[4];
#pragma unroll
    for (int r = 0; r < 4; ++r) {
      int row = row0 + w * 16 + (l >> 4) * 4 + r;
      g0[r] = (row < N_NODES) ? batch[row] : -1;
    }
#pragma unroll
    for (int ct = 0; ct < 8; ++ct) {
      int col = ct * 16 + (l & 15);
      float s = 0.f;
      int cur = g0[0];
#pragma unroll
      for (int r = 0; r < 4; ++r) {
        if (g0[r] != cur) {
          if (cur >= 0) atomicAdd(&out[(size_t)cur * FDIM + col], s);
          cur = g0[r];
          s = 0.f;
        }
        if (g0[r] >= 0) s += acc[ct][r] + bv[ct];
      }
      if (cur >= 0) atomicAdd(&out[(size_t)cur * FDIM + col], s);
    }
  }
}

extern "C" void kernel_launch(void* const* d_in, const int* in_sizes, int n_in,
                              void* d_out, int out_size, void* d_ws,
                              size_t ws_size, hipStream_t stream) {
  const int* x_type = (const int*)d_in[0];
  const int* edge_index = (const int*)d_in[1];
  const int* batch = (const int*)d_in[2];
  const float* emb = (const float*)d_in[3];
  const float* W1 = (const float*)d_in[4];
  const float* b1 = (const float*)d_in[5];
  const float* W2 = (const float*)d_in[6];
  const float* b2 = (const float*)d_in[7];
  float* out = (float*)d_out;

  const int* src = edge_index;
  const int* dst = edge_index + N_EDGES;

  char* p = (char*)d_ws;
  size_t off = 0;
  auto alloc = [&](size_t bytes) {
    void* r = p + off;
    off = (off + bytes + 255) & ~(size_t)255;
    return r;
  };
  float* dis = (float*)alloc(N_NODES * 4);
  int* cnt = (int*)alloc(N_NODES * 4);
  int* row_ptr = (int*)alloc((N_NODES + 1) * 4);
  int* fill = (int*)alloc(N_NODES * 4);
  int* blk = (int*)alloc(1024);
  int4* csr = (int4*)alloc((size_t)N_EDGES * 16);
  unsigned short* Wt1 = (unsigned short*)alloc(128 * 128 * 2);
  unsigned short* Wt2 = (unsigned short*)alloc(128 * 128 * 2);
  unsigned int* y1 = (unsigned int*)alloc((size_t)N_NODES * 64 * 4);
  (void)ws_size;

  k_init<<<256, 256, 0, stream>>>(cnt, fill, out);
  k_count<<<(N_EDGES + 255) / 256, 256, 0, stream>>>(dst, cnt);
  k_scan1<<<NB, 256, 0, stream>>>(cnt, row_ptr, blk);
  k_scan2<<<1, 256, 0, stream>>>(blk);
  k_scan3<<<NB, 256, 0, stream>>>(cnt, row_ptr, blk, dis);
  k_fill<<<(N_EDGES + 255) / 256, 256, 0, stream>>>(src, dst, x_type, row_ptr,
                                                    fill, dis, csr);
  k_prep_w<<<128, 256, 0, stream>>>(W1, W2, Wt1, Wt2);
  k_layer<1><<<(N_NODES + 63) / 64, 256, 0, stream>>>(
      x_type, emb, nullptr, Wt1, b1, row_ptr, csr, dis, (unsigned short*)y1,
      nullptr, nullptr);
  k_layer<2><<<(N_NODES + 63) / 64, 256, 0, stream>>>(
      nullptr, nullptr, y1, Wt2, b2, row_ptr, csr, dis, nullptr, batch, out);
}

// Round 4
// 205.240 us; speedup vs baseline: 1.5967x; 1.5967x over previous
//
#include <hip/hip_runtime.h>

#define N_NODES 50000
#define N_EDGES 800000
#define N_GRAPHS 512
#define FDIM 128
#define NTYPES_PAD 1000

constexpr int SCAN_TILE = 256;
constexpr int NB = (N_NODES + SCAN_TILE - 1) / SCAN_TILE;  // 196

typedef __bf16 bf16x8 __attribute__((ext_vector_type(8)));
typedef float f32x4 __attribute__((ext_vector_type(4)));
union BF8 { bf16x8 v; unsigned short u[8]; };

__device__ __forceinline__ unsigned short f2bf(float f) {
  unsigned int u = __float_as_uint(f);
  unsigned int r = (u + 0x7FFFu + ((u >> 16) & 1u)) >> 16;
  return (unsigned short)r;
}
__device__ __forceinline__ float bflo(unsigned int v) {
  return __uint_as_float(v << 16);
}
__device__ __forceinline__ float bfhi(unsigned int v) {
  return __uint_as_float(v & 0xFFFF0000u);
}

__global__ void k_init(int* __restrict__ cnt, int* __restrict__ fill,
                       float* __restrict__ out) {
  int i = blockIdx.x * blockDim.x + threadIdx.x;
  if (i < N_NODES) { cnt[i] = 0; fill[i] = 0; }
  if (i < N_GRAPHS * FDIM) out[i] = 0.0f;
}

__global__ void k_count(const int* __restrict__ dst, int* __restrict__ cnt) {
  int e = blockIdx.x * blockDim.x + threadIdx.x;
  if (e < N_EDGES) atomicAdd(&cnt[dst[e]], 1);
}

__global__ void k_scan1(const int* __restrict__ cnt, int* __restrict__ row_ptr,
                        int* __restrict__ blk) {
  __shared__ int s[SCAN_TILE];
  int t = threadIdx.x;
  int i = blockIdx.x * SCAN_TILE + t;
  int v = (i < N_NODES) ? cnt[i] : 0;
  s[t] = v;
  __syncthreads();
  for (int d = 1; d < SCAN_TILE; d <<= 1) {
    int u = (t >= d) ? s[t - d] : 0;
    __syncthreads();
    s[t] += u;
    __syncthreads();
  }
  if (i < N_NODES) row_ptr[i] = s[t] - v;
  if (t == SCAN_TILE - 1) blk[blockIdx.x] = s[t];
}

__global__ void k_scan2(int* __restrict__ blk) {
  __shared__ int s[256];
  int t = threadIdx.x;
  int v = (t < NB) ? blk[t] : 0;
  s[t] = v;
  __syncthreads();
  for (int d = 1; d < 256; d <<= 1) {
    int u = (t >= d) ? s[t - d] : 0;
    __syncthreads();
    s[t] += u;
    __syncthreads();
  }
  if (t < NB) blk[t] = s[t] - v;
}

__global__ void k_scan3(const int* __restrict__ cnt, int* __restrict__ row_ptr,
                        const int* __restrict__ blk, float* __restrict__ dis) {
  int i = blockIdx.x * blockDim.x + threadIdx.x;
  if (i < N_NODES) {
    row_ptr[i] += blk[blockIdx.x];
    dis[i] = rsqrtf((float)(cnt[i] + 1));
  }
  if (i == 0) row_ptr[N_NODES] = N_EDGES;
}

// csr_t: (x_type[src], norm)  csr_s: (src, norm)
__global__ void k_fill(const int* __restrict__ src, const int* __restrict__ dst,
                       const int* __restrict__ x_type,
                       const int* __restrict__ row_ptr, int* __restrict__ fill,
                       const float* __restrict__ dis, int2* __restrict__ csr_t,
                       int2* __restrict__ csr_s) {
  int e = blockIdx.x * blockDim.x + threadIdx.x;
  if (e >= N_EDGES) return;
  int s = src[e], d = dst[e];
  int pos = row_ptr[d] + atomicAdd(&fill[d], 1);
  int nb = __float_as_int(dis[s] * dis[d]);
  csr_t[pos] = make_int2(x_type[s], nb);
  csr_s[pos] = make_int2(s, nb);
}

// W [128x128] f32 (k,n) -> Wt bf16 [n][k ^ ((n&15)<<3)]
__global__ void k_prep_w(const float* __restrict__ W0,
                         const float* __restrict__ W1,
                         unsigned short* __restrict__ Wt0,
                         unsigned short* __restrict__ Wt1) {
  int id = blockIdx.x * blockDim.x + threadIdx.x;  // 32768
  const float* W = (id >> 14) ? W1 : W0;
  unsigned short* Wt = (id >> 14) ? Wt1 : Wt0;
  int rem = id & 16383;
  int k = rem >> 7, n = rem & 127;
  Wt[n * 128 + (k ^ ((n & 15) << 3))] = f2bf(W[k * 128 + n]);
}

// T1 = emb @ W1  [1000 x 128] bf16. 4 waves/block, 64 rows/block.
__global__ __launch_bounds__(256) void k_embw(
    const float* __restrict__ emb, const unsigned short* __restrict__ Wt,
    unsigned short* __restrict__ T1) {
  __shared__ unsigned short Ws[128 * 128];
  int t = threadIdx.x, w = t >> 6, l = t & 63;
  {
    const float4* g = (const float4*)Wt;
    float4* ls = (float4*)Ws;
    for (int i = t; i < 2048; i += 256) ls[i] = g[i];
  }
  int row0 = blockIdx.x * 64 + w * 16;
  int arow = row0 + (l & 15);
  bool ok = arow < NTYPES_PAD;
  bf16x8 a[4];
#pragma unroll
  for (int ks = 0; ks < 4; ++ks) {
    BF8 av;
    const float* ap = emb + (size_t)arow * FDIM + (l >> 4) * 8 + ks * 32;
#pragma unroll
    for (int i = 0; i < 8; ++i) av.u[i] = ok ? f2bf(ap[i]) : 0;
    a[ks] = av.v;
  }
  __syncthreads();
  f32x4 acc[8] = {};
#pragma unroll
  for (int ks = 0; ks < 4; ++ks) {
#pragma unroll
    for (int ct = 0; ct < 8; ++ct) {
      int n = ct * 16 + (l & 15);
      int kk = (ks * 32 + (l >> 4) * 8) ^ ((n & 15) << 3);
      bf16x8 b = *(const bf16x8*)&Ws[n * 128 + kk];
      acc[ct] =
          __builtin_amdgcn_mfma_f32_16x16x32_bf16(a[ks], b, acc[ct], 0, 0, 0);
    }
  }
#pragma unroll
  for (int ct = 0; ct < 8; ++ct) {
    int col = ct * 16 + (l & 15);
#pragma unroll
    for (int r = 0; r < 4; ++r) {
      int row = row0 + (l >> 4) * 4 + r;
      if (row < NTYPES_PAD) T1[row * FDIM + col] = f2bf(acc[ct][r]);
    }
  }
}

// Layer-1 aggregate from L2-resident T1: 1 wave/node, 2 feats/lane.
// y1[node] = relu( d_i^2*T1[type[i]] + sum norm*T1[type[src]] + b1 )
__global__ void k_agg1(const int* __restrict__ x_type,
                       const unsigned short* __restrict__ T1,
                       const float* __restrict__ b1,
                       const int* __restrict__ row_ptr,
                       const int2* __restrict__ csr_t,
                       const float* __restrict__ dis,
                       unsigned int* __restrict__ y1) {
  int gid = blockIdx.x * blockDim.x + threadIdx.x;
  int node = gid >> 6;
  int lane = gid & 63;
  if (node >= N_NODES) return;
  const unsigned int* T = (const unsigned int*)T1;
  float di = dis[node];
  float w0 = di * di;
  unsigned int v = T[(size_t)x_type[node] * 64 + lane];
  float ax = bflo(v) * w0, ay = bfhi(v) * w0;
  int j = row_ptr[node], end = row_ptr[node + 1];
  for (; j + 4 <= end; j += 4) {
    int2 e0 = csr_t[j], e1 = csr_t[j + 1], e2 = csr_t[j + 2], e3 = csr_t[j + 3];
    unsigned int u0 = T[(size_t)e0.x * 64 + lane];
    unsigned int u1 = T[(size_t)e1.x * 64 + lane];
    unsigned int u2 = T[(size_t)e2.x * 64 + lane];
    unsigned int u3 = T[(size_t)e3.x * 64 + lane];
    float n0 = __int_as_float(e0.y), n1 = __int_as_float(e1.y);
    float n2 = __int_as_float(e2.y), n3 = __int_as_float(e3.y);
    ax = fmaf(bflo(u0), n0, ax); ay = fmaf(bfhi(u0), n0, ay);
    ax = fmaf(bflo(u1), n1, ax); ay = fmaf(bfhi(u1), n1, ay);
    ax = fmaf(bflo(u2), n2, ax); ay = fmaf(bfhi(u2), n2, ay);
    ax = fmaf(bflo(u3), n3, ax); ay = fmaf(bfhi(u3), n3, ay);
  }
  for (; j < end; ++j) {
    int2 e = csr_t[j];
    unsigned int u = T[(size_t)e.x * 64 + lane];
    float nw = __int_as_float(e.y);
    ax = fmaf(bflo(u), nw, ax);
    ay = fmaf(bfhi(u), nw, ay);
  }
  float2 bb = ((const float2*)b1)[lane];
  ax = fmaxf(ax + bb.x, 0.f);
  ay = fmaxf(ay + bb.y, 0.f);
  y1[(size_t)node * 64 + lane] = (unsigned int)f2bf(ax) |
                                 ((unsigned int)f2bf(ay) << 16);
}

// M = y1 @ W2 (bf16, no bias). 8 waves, 128 rows/block, LDS-staged epilogue.
__global__ __launch_bounds__(512) void k_gemm2(
    const unsigned short* __restrict__ x, const unsigned short* __restrict__ Wt,
    unsigned short* __restrict__ y) {
  __shared__ unsigned short Ws[128 * 128];  // 32 KB: W, then reused for C
  int t = threadIdx.x, w = t >> 6, l = t & 63;
  {
    const char* g = (const char*)Wt + t * 16;
#pragma unroll
    for (int i = 0; i < 4; ++i) {
      __builtin_amdgcn_global_load_lds(
          (const __attribute__((address_space(1))) unsigned int*)(g + i * 8192),
          (__attribute__((address_space(3))) unsigned int*)((char*)Ws + t * 16 +
                                                            i * 8192),
          16, 0, 0);
    }
  }
  int row0 = blockIdx.x * 128 + w * 16;
  int arow = row0 + (l & 15);
  bool ok = arow < N_NODES;
  bf16x8 a[4];
  {
    bf16x8 z{};
    const bf16x8* ap = (const bf16x8*)(x + (size_t)arow * FDIM + (l >> 4) * 8);
#pragma unroll
    for (int ks = 0; ks < 4; ++ks) a[ks] = ok ? ap[ks * 4] : z;
  }
  __syncthreads();  // drains vmcnt (global_load_lds) + all waves ready

  f32x4 acc[8] = {};
#pragma unroll
  for (int ks = 0; ks < 4; ++ks) {
#pragma unroll
    for (int ct = 0; ct < 8; ++ct) {
      int n = ct * 16 + (l & 15);
      int kk = (ks * 32 + (l >> 4) * 8) ^ ((n & 15) << 3);
      bf16x8 b = *(const bf16x8*)&Ws[n * 128 + kk];
      acc[ct] =
          __builtin_amdgcn_mfma_f32_16x16x32_bf16(a[ks], b, acc[ct], 0, 0, 0);
    }
  }
  __syncthreads();  // all B-frag reads done; reuse Ws for C tile

  // wave-private 16x128 C region -> coalesced 16B/lane stores
  unsigned short* C = Ws + w * 16 * 128;
#pragma unroll
  for (int r = 0; r < 4; ++r) {
    int lr = (l >> 4) * 4 + r;
#pragma unroll
    for (int ct = 0; ct < 8; ++ct)
      C[lr * 128 + ct * 16 + (l & 15)] = f2bf(acc[ct][r]);
  }
#pragma unroll
  for (int i = 0; i < 4; ++i) {
    int row = row0 + i * 4 + (l >> 4);
    if (row < N_NODES) {
      float4 v = *(const float4*)((const char*)C + i * 1024 + l * 16);
      *(float4*)((char*)y + (size_t)row0 * 256 + i * 1024 + l * 16) = v;
    }
  }
}

// Layer-2 aggregate + pool: 1 wave/node; atomicAdd into out[batch[node]].
__global__ void k_agg2(const unsigned int* __restrict__ M,
                       const float* __restrict__ b2,
                       const int* __restrict__ row_ptr,
                       const int2* __restrict__ csr_s,
                       const float* __restrict__ dis,
                       const int* __restrict__ batch,
                       float* __restrict__ out) {
  int gid = blockIdx.x * blockDim.x + threadIdx.x;
  int node = gid >> 6;
  int lane = gid & 63;
  if (node >= N_NODES) return;
  float di = dis[node];
  float w0 = di * di;
  unsigned int v = M[(size_t)node * 64 + lane];
  float ax = bflo(v) * w0, ay = bfhi(v) * w0;
  int j = row_ptr[node], end = row_ptr[node + 1];
  for (; j + 4 <= end; j += 4) {
    int2 e0 = csr_s[j], e1 = csr_s[j + 1], e2 = csr_s[j + 2], e3 = csr_s[j + 3];
    unsigned int u0 = M[(size_t)e0.x * 64 + lane];
    unsigned int u1 = M[(size_t)e1.x * 64 + lane];
    unsigned int u2 = M[(size_t)e2.x * 64 + lane];
    unsigned int u3 = M[(size_t)e3.x * 64 + lane];
    float n0 = __int_as_float(e0.y), n1 = __int_as_float(e1.y);
    float n2 = __int_as_float(e2.y), n3 = __int_as_float(e3.y);
    ax = fmaf(bflo(u0), n0, ax); ay = fmaf(bfhi(u0), n0, ay);
    ax = fmaf(bflo(u1), n1, ax); ay = fmaf(bfhi(u1), n1, ay);
    ax = fmaf(bflo(u2), n2, ax); ay = fmaf(bfhi(u2), n2, ay);
    ax = fmaf(bflo(u3), n3, ax); ay = fmaf(bfhi(u3), n3, ay);
  }
  for (; j < end; ++j) {
    int2 e = csr_s[j];
    unsigned int u = M[(size_t)e.x * 64 + lane];
    float nw = __int_as_float(e.y);
    ax = fmaf(bflo(u), nw, ax);
    ay = fmaf(bfhi(u), nw, ay);
  }
  float2 bb = ((const float2*)b2)[lane];
  int g = batch[node];
  atomicAdd(&out[(size_t)g * FDIM + 2 * lane], ax + bb.x);
  atomicAdd(&out[(size_t)g * FDIM + 2 * lane + 1], ay + bb.y);
}

extern "C" void kernel_launch(void* const* d_in, const int* in_sizes, int n_in,
                              void* d_out, int out_size, void* d_ws,
                              size_t ws_size, hipStream_t stream) {
  const int* x_type = (const int*)d_in[0];
  const int* edge_index = (const int*)d_in[1];
  const int* batch = (const int*)d_in[2];
  const float* emb = (const float*)d_in[3];
  const float* W1 = (const float*)d_in[4];
  const float* b1 = (const float*)d_in[5];
  const float* W2 = (const float*)d_in[6];
  const float* b2 = (const float*)d_in[7];
  float* out = (float*)d_out;

  const int* src = edge_index;
  const int* dst = edge_index + N_EDGES;

  char* p = (char*)d_ws;
  size_t off = 0;
  auto alloc = [&](size_t bytes) {
    void* r = p + off;
    off = (off + bytes + 255) & ~(size_t)255;
    return r;
  };
  float* dis = (float*)alloc(N_NODES * 4);
  int* cnt = (int*)alloc(N_NODES * 4);
  int* row_ptr = (int*)alloc((N_NODES + 1) * 4);
  int* fill = (int*)alloc(N_NODES * 4);
  int* blk = (int*)alloc(1024);
  int2* csr_t = (int2*)alloc((size_t)N_EDGES * 8);
  int2* csr_s = (int2*)alloc((size_t)N_EDGES * 8);
  unsigned short* Wt1 = (unsigned short*)alloc(128 * 128 * 2);
  unsigned short* Wt2 = (unsigned short*)alloc(128 * 128 * 2);
  unsigned short* T1 = (unsigned short*)alloc((size_t)NTYPES_PAD * FDIM * 2);
  unsigned int* y1 = (unsigned int*)alloc((size_t)N_NODES * 64 * 4);
  unsigned int* M = (unsigned int*)alloc((size_t)N_NODES * 64 * 4);
  (void)ws_size;

  k_init<<<256, 256, 0, stream>>>(cnt, fill, out);
  k_count<<<(N_EDGES + 255) / 256, 256, 0, stream>>>(dst, cnt);
  k_scan1<<<NB, 256, 0, stream>>>(cnt, row_ptr, blk);
  k_scan2<<<1, 256, 0, stream>>>(blk);
  k_scan3<<<NB, 256, 0, stream>>>(cnt, row_ptr, blk, dis);
  k_fill<<<(N_EDGES + 255) / 256, 256, 0, stream>>>(src, dst, x_type, row_ptr,
                                                    fill, dis, csr_t, csr_s);
  k_prep_w<<<128, 256, 0, stream>>>(W1, W2, Wt1, Wt2);
  k_embw<<<(NTYPES_PAD + 63) / 64, 256, 0, stream>>>(emb, Wt1, T1);
  k_agg1<<<(N_NODES * 64 + 255) / 256, 256, 0, stream>>>(
      x_type, T1, b1, row_ptr, csr_t, dis, y1);
  k_gemm2<<<(N_NODES + 127) / 128, 512, 0, stream>>>(
      (const unsigned short*)y1, Wt2, (unsigned short*)M);
  k_agg2<<<(N_NODES * 64 + 255) / 256, 256, 0, stream>>>(
      M, b2, row_ptr, csr_s, dis, batch, out);
}